// Round 14
// baseline (4085.558 us; speedup 1.0000x reference)
//
#include <hip/hip_runtime.h>
#include <stdint.h>

#define NB 16
#define HH 128
#define WW 128
#define L (HH*WW)        // 16384
#define CIN 3
#define HID 256
#define NC 21
#define CHUNK 256
#define WARM 512
#define NCHUNKS (L/CHUNK)   // 64
#define T_PER 32            // t's per wave in k_bp
#define NPACK (L/4)         // 4096 packs of 4 timesteps

// ---------------- K1: conv -> fp32 emissions, stored TRANSPOSED em_T[b][c][t] ----------------
// fp64 accumulate (round once to fp32 = correctly rounded), fp32 elementwise bias in ref order.
__global__ __launch_bounds__(256) void k_conv(
    const float* __restrict__ x, const float* __restrict__ w1,
    const float* __restrict__ b1, const float* __restrict__ w2,
    const float* __restrict__ b2, float* __restrict__ emT)
{
    int tid = threadIdx.x;
    int g  = blockIdx.x * 256 + tid;      // 0..B*L-1
    int b  = g >> 14;
    int t  = g & (L-1);
    int y  = t >> 7;
    int xx = t & (WW-1);

    double p[27];
    const float* xb = x + (size_t)b * CIN * L;
    #pragma unroll
    for (int ic = 0; ic < CIN; ++ic) {
        #pragma unroll
        for (int ky = 0; ky < 3; ++ky) {
            #pragma unroll
            for (int kx = 0; kx < 3; ++kx) {
                int yy = y + ky - 1, xc = xx + kx - 1;
                float v = 0.f;
                if (yy >= 0 && yy < HH && xc >= 0 && xc < WW)
                    v = xb[ic * L + yy * WW + xc];
                p[ic*9 + ky*3 + kx] = (double)v;
            }
        }
    }

    double acc[NC];
    #pragma unroll
    for (int c = 0; c < NC; ++c) acc[c] = 0.0;

    #pragma unroll 2
    for (int oc = 0; oc < HID; ++oc) {
        double hv = 0.0;                              // conv1 accum
        #pragma unroll
        for (int j = 0; j < 27; ++j) hv += (double)w1[oc*27 + j] * p[j];
        float h32 = (float)hv;                        // round conv1 to fp32
        h32 = h32 + b1[oc];                           // fp32 elementwise bias
        h32 = fmaxf(h32, 0.f);                        // relu (fp32)
        double hd = (double)h32;
        #pragma unroll
        for (int c = 0; c < NC; ++c) acc[c] += (double)w2[c*HID + oc] * hd;
    }
    float* dstb = emT + (size_t)b * NC * L;
    #pragma unroll
    for (int c = 0; c < NC; ++c) {
        float e32 = (float)acc[c];                    // round conv2 to fp32
        dstb[(size_t)c * L + t] = e32 + b2[c];        // transposed store (coalesced in t)
    }
}

// ---------------- K2a: DPP-systolic fp32 score recursion, one batch per wave ----------------
// s'[n] = fl( max_p fl(s[p]+T[p][n]) + e[n] ) — bitwise equal to ref by RNE monotonicity.
// NO DS ops in the loop: cross-lane transport is v_mov_dpp wave_ror:1 (VALU speed).
// Lanes: j=0..63, p = j mod 21 (3 copies; lane 63 = bubble, injects -inf).
// 64 accumulators rotate up one lane/iter; at iter r lane j injects c[r]=fl(sv+tcd[r]),
// tcd[r] = T[p][nu(j,r)], nu = ((j+21-r)&63) mod 21 — static per-iteration register.
// After 22 injections / 21 rotations, each lane's acc = exact 21-max for ITS OWN state:
// sv update is lane-local, no redistribution level at all.
#define ROT1(V) __int_as_float(__builtin_amdgcn_update_dpp( \
    0, __float_as_int(V), 0x13C /*wave_ror:1*/, 0xF, 0xF, true))

__global__ __launch_bounds__(64) void k_scores(
    const float* __restrict__ emT, const float* __restrict__ start,
    const float* __restrict__ endt, const float* __restrict__ trans,
    float* __restrict__ sc, int* __restrict__ last_tag)
{
    __shared__ float fin[NC];
    int l = threadIdx.x;
    int b = blockIdx.x;
    int p = l % NC;                          // lane 63 -> p=0 (extra copy)
    bool storer = (l >= NC && l < 2*NC);     // lanes 21..41: clean copy for stores
    int n = storer ? (l - NC) : 0;

    const float4* er4 = (const float4*)(emT + ((size_t)b * NC + p) * L);
    float*        scp = sc + (size_t)b * NC * L;          // 84 floats per pack

    // diagonal transition registers
    float tcd[22];
    #pragma unroll
    for (int r = 0; r < 22; ++r) {
        int nu = ((l + 21 - r) & 63) % NC;
        tcd[r] = (l == 63) ? -1.0e30f : trans[p*NC + nu];
    }
    #pragma unroll
    for (int r = 0; r < 22; ++r) asm volatile("" : "+v"(tcd[r]));  // pin in VGPRs

    float sv;   // my state's current score s[p] (lane-local)

    #define STEP(EV, OUT) { \
        float c[22]; \
        _Pragma("unroll") \
        for (int r = 0; r < 22; ++r) c[r] = sv + tcd[r];   /* fl(s+T), off-path */ \
        float macc = c[0]; \
        _Pragma("unroll") \
        for (int r = 1; r < 22; ++r) macc = fmaxf(ROT1(macc), c[r]); \
        OUT = macc + (EV);                                  /* exact 21-max, fl(+e) */ \
        sv = OUT; }

    float4 ebuf0 = er4[0];
    float4 ebuf1 = er4[1];

    // ---- pack 0 (t=0 init + t=1..3) ----
    float v0 = ebuf0.x + start[p];      // s0 = fl(em[0]+start), ref order, lane-local
    sv = v0;
    {
        float4 ev = ebuf0;
        ebuf0 = er4[2];
        float a1v, a2v, a3v;
        STEP(ev.y, a1v)
        STEP(ev.z, a2v)
        STEP(ev.w, a3v)
        if (storer) *(float4*)(scp + n*4) = make_float4(v0, a1v, a2v, a3v);
    }

    // ---- packs 1..4095 ----
    for (int k = 1; k < NPACK; ++k) {
        float4 ev = (k & 1) ? ebuf1 : ebuf0;
        int kp = k + 2; if (kp > NPACK-1) kp = NPACK-1;
        if (k & 1) ebuf1 = er4[kp]; else ebuf0 = er4[kp];

        float b0, b1_, b2_, b3;
        STEP(ev.x, b0)
        STEP(ev.y, b1_)
        STEP(ev.z, b2_)
        STEP(ev.w, b3)
        if (storer) *(float4*)(scp + k*84 + n*4) = make_float4(b0, b1_, b2_, b3);
    }
    #undef STEP

    if (storer) fin[n] = sv;
    __syncthreads();
    if (l == 0) {
        float bv = fin[0] + endt[0]; int bt = 0;
        #pragma unroll
        for (int j = 1; j < NC; ++j) {
            float v = fin[j] + endt[j];
            if (v > bv) { bv = v; bt = j; }
        }
        last_tag[b] = bt;
    }
}

// ---------------- K2b: parallel backpointer recovery ----------------
// bp[t][n] = first p with fl(fl(s_{t-1}[p]+T[p][n])+e[t][n]) == s_t[n]
__global__ __launch_bounds__(256) void k_bp(
    const float* __restrict__ emT, const float* __restrict__ sc,
    const float* __restrict__ trans, uint8_t* __restrict__ bp)
{
    int wave = threadIdx.x >> 6;
    int lane = threadIdx.x & 63;
    int ne   = lane < NC ? lane : NC-1;

    int bidx  = blockIdx.x;
    int b     = bidx >> 7;                              // 128 blocks per batch
    int tbase = (bidx & 127) * (4*T_PER) + wave*T_PER;

    const float* emb = emT + (size_t)b * NC * L;
    const float* scp = sc  + (size_t)b * NC * L;
    uint8_t*     bpb = bp  + (size_t)b * L * NC;

    float tc[NC];
    #pragma unroll
    for (int pp = 0; pp < NC; ++pp) tc[pp] = trans[pp*NC + ne];

    for (int t = tbase; t < tbase + T_PER; ++t) {
        if (t == 0) continue;
        float target = scp[(t>>2)*84 + ne*4 + (t&3)];
        float e      = emb[(size_t)ne * L + t];
        const float* sp = scp + ((t-1)>>2)*84 + ((t-1)&3);
        int fi = 0;
        #pragma unroll
        for (int pp = NC-1; pp >= 0; --pp) {
            float cand = (sp[pp*4] + tc[pp]) + e;
            if (cand == target) fi = pp;
        }
        if (lane < NC) bpb[(size_t)t * NC + ne] = (uint8_t)fi;
    }
}

// ---------------- K3: chunk-parallel backtrack (integer, exact) ----------------
__global__ __launch_bounds__(64) void k_backtrack(
    const uint8_t* __restrict__ bp, const int* __restrict__ last_tag,
    int* __restrict__ out)
{
    int blk = blockIdx.x;
    int b   = blk >> 6;
    int k   = blk & (NCHUNKS-1);
    int cs  = k * CHUNK;
    int ce  = cs + CHUNK;
    int sp  = ce - 1 + WARM; if (sp > L-1) sp = L-1;
    int tag = (sp == L-1) ? last_tag[b] : 0;
    const uint8_t* bpb = bp + (size_t)b * L * NC;
    int* ob = out + (size_t)b * L;
    for (int t = sp;; --t) {
        if (t < ce) { if (threadIdx.x == 0) ob[t] = tag; }
        if (t == cs) break;
        tag = (int)bpb[(size_t)t * NC + tag];
    }
}

extern "C" void kernel_launch(void* const* d_in, const int* in_sizes, int n_in,
                              void* d_out, int out_size, void* d_ws, size_t ws_size,
                              hipStream_t stream) {
    const float* x  = (const float*)d_in[0];
    const float* w1 = (const float*)d_in[1];
    const float* b1 = (const float*)d_in[2];
    const float* w2 = (const float*)d_in[3];
    const float* b2 = (const float*)d_in[4];
    const float* st = (const float*)d_in[5];
    const float* en = (const float*)d_in[6];
    const float* tr = (const float*)d_in[7];
    int* out = (int*)d_out;

    char* ws = (char*)d_ws;
    float*   em = (float*)ws;                                    // em_T: 22,020,096 B
    float*   sc = (float*)(ws + (size_t)NB*L*NC*4);              // packed scores: 22,020,096 B
    uint8_t* bp = (uint8_t*)(ws + (size_t)NB*L*NC*8);            // 5,505,024 B
    int*     lt = (int*)(ws + (size_t)NB*L*NC*9);                // int[NB]

    k_conv     <<<dim3(NB*L/256),   dim3(256), 0, stream>>>(x, w1, b1, w2, b2, em);
    k_scores   <<<dim3(NB),         dim3(64),  0, stream>>>(em, st, en, tr, sc, lt);
    k_bp       <<<dim3(NB*128),     dim3(256), 0, stream>>>(em, sc, tr, bp);
    k_backtrack<<<dim3(NB*NCHUNKS), dim3(64),  0, stream>>>(bp, lt, out);
}

// Round 15
// 3348.943 us; speedup vs baseline: 1.2200x; 1.2200x over previous
//
#include <hip/hip_runtime.h>
#include <stdint.h>

#define NB 16
#define HH 128
#define WW 128
#define L (HH*WW)        // 16384
#define CIN 3
#define HID 256
#define NC 21
#define CHUNK 256
#define WARM 512
#define NCHUNKS (L/CHUNK)   // 64
#define T_PER 32            // t's per wave in k_bp
#define NPACK (L/4)         // 4096 packs of 4 timesteps

// ---------------- K1: conv -> fp32 emissions, stored TRANSPOSED em_T[b][c][t] ----------------
// fp64 accumulate (round once to fp32 = correctly rounded), fp32 elementwise bias in ref order.
__global__ __launch_bounds__(256) void k_conv(
    const float* __restrict__ x, const float* __restrict__ w1,
    const float* __restrict__ b1, const float* __restrict__ w2,
    const float* __restrict__ b2, float* __restrict__ emT)
{
    int tid = threadIdx.x;
    int g  = blockIdx.x * 256 + tid;      // 0..B*L-1
    int b  = g >> 14;
    int t  = g & (L-1);
    int y  = t >> 7;
    int xx = t & (WW-1);

    double p[27];
    const float* xb = x + (size_t)b * CIN * L;
    #pragma unroll
    for (int ic = 0; ic < CIN; ++ic) {
        #pragma unroll
        for (int ky = 0; ky < 3; ++ky) {
            #pragma unroll
            for (int kx = 0; kx < 3; ++kx) {
                int yy = y + ky - 1, xc = xx + kx - 1;
                float v = 0.f;
                if (yy >= 0 && yy < HH && xc >= 0 && xc < WW)
                    v = xb[ic * L + yy * WW + xc];
                p[ic*9 + ky*3 + kx] = (double)v;
            }
        }
    }

    double acc[NC];
    #pragma unroll
    for (int c = 0; c < NC; ++c) acc[c] = 0.0;

    #pragma unroll 2
    for (int oc = 0; oc < HID; ++oc) {
        double hv = 0.0;                              // conv1 accum
        #pragma unroll
        for (int j = 0; j < 27; ++j) hv += (double)w1[oc*27 + j] * p[j];
        float h32 = (float)hv;                        // round conv1 to fp32
        h32 = h32 + b1[oc];                           // fp32 elementwise bias
        h32 = fmaxf(h32, 0.f);                        // relu (fp32)
        double hd = (double)h32;
        #pragma unroll
        for (int c = 0; c < NC; ++c) acc[c] += (double)w2[c*HID + oc] * hd;
    }
    float* dstb = emT + (size_t)b * NC * L;
    #pragma unroll
    for (int c = 0; c < NC; ++c) {
        float e32 = (float)acc[c];                    // round conv2 to fp32
        dstb[(size_t)c * L + t] = e32 + b2[c];        // transposed store (coalesced in t)
    }
}

// ---------------- K2a: flat single-level bpermute recursion, one batch per wave ----------------
// s'[n] = fl( max_p fl(s[p]+T[p][n]) + e[n] ) — bitwise equal to ref by RNE monotonicity.
// Transport ladder (measured R6-R14): DPP-chain 525 / swizzle 456 / LDS-rt 365 / readlane 354
// / 2-level bpermute 314 cyc per step. This round: ONE dependent DS level — every lane
// gathers all 21 scores via 21 pipelined ds_bpermute ops, all sourced from the single
// just-computed sv register; lanes 0..20 hold the canonical copy (gather addrs p*4, p<21).
// Path ~ max(21x6 issue, 120 lat) + tail adds + max3 tree + e-add ~ 260 cyc.
__global__ __launch_bounds__(64) void k_scores(
    const float* __restrict__ emT, const float* __restrict__ start,
    const float* __restrict__ endt, const float* __restrict__ trans,
    float* __restrict__ sc, int* __restrict__ last_tag)
{
    __shared__ float fin[NC];
    int l = threadIdx.x;
    int b = blockIdx.x;
    int n = l % NC;                          // lanes >=21 shadow n = l-21 / l-42

    const float4* er4 = (const float4*)(emT + ((size_t)b * NC + n) * L);
    float*        scp = sc + (size_t)b * NC * L;          // 84 floats per pack

    float tc[NC];
    #pragma unroll
    for (int pp = 0; pp < NC; ++pp) tc[pp] = trans[pp*NC + n];
    #pragma unroll
    for (int pp = 0; pp < NC; ++pp) asm volatile("" : "+v"(tc[pp]));  // pin in VGPRs

    float sv;   // my state's current score s[n] (canonical in lanes 0..20)

    #define BPERM(A,V) __int_as_float(__builtin_amdgcn_ds_bpermute((A), __float_as_int(V)))

    #define STEP(EV, OUT) { \
        float w[NC]; \
        _Pragma("unroll") \
        for (int pp = 0; pp < NC; ++pp) w[pp] = BPERM(pp*4, sv) + tc[pp];  /* fl(s+T) */ \
        float m[7]; \
        _Pragma("unroll") \
        for (int i = 0; i < 7; ++i) m[i] = fmaxf(fmaxf(w[3*i], w[3*i+1]), w[3*i+2]); \
        float a0 = fmaxf(fmaxf(m[0], m[1]), m[2]); \
        float a1 = fmaxf(fmaxf(m[3], m[4]), m[5]); \
        OUT = fmaxf(fmaxf(a0, a1), m[6]) + (EV);          /* exact 21-max, fl(+e) */ \
        sv = OUT; }

    float4 ebuf0 = er4[0];
    float4 ebuf1 = er4[1];

    // ---- pack 0 (t=0 init + t=1..3) ----
    float v0 = ebuf0.x + start[n];      // s0 = fl(em[0]+start), ref order
    sv = v0;
    {
        float4 ev = ebuf0;
        ebuf0 = er4[2];
        float a1v, a2v, a3v;
        STEP(ev.y, a1v)
        STEP(ev.z, a2v)
        STEP(ev.w, a3v)
        if (l < NC) *(float4*)(scp + n*4) = make_float4(v0, a1v, a2v, a3v);
    }

    // ---- packs 1..4095 ----
    for (int k = 1; k < NPACK; ++k) {
        float4 ev = (k & 1) ? ebuf1 : ebuf0;
        int kp = k + 2; if (kp > NPACK-1) kp = NPACK-1;
        if (k & 1) ebuf1 = er4[kp]; else ebuf0 = er4[kp];

        float b0, b1_, b2_, b3;
        STEP(ev.x, b0)
        STEP(ev.y, b1_)
        STEP(ev.z, b2_)
        STEP(ev.w, b3)
        if (l < NC) *(float4*)(scp + k*84 + n*4) = make_float4(b0, b1_, b2_, b3);
    }
    #undef STEP
    #undef BPERM

    if (l < NC) fin[n] = sv;
    __syncthreads();
    if (l == 0) {
        float bv = fin[0] + endt[0]; int bt = 0;
        #pragma unroll
        for (int j = 1; j < NC; ++j) {
            float v = fin[j] + endt[j];
            if (v > bv) { bv = v; bt = j; }
        }
        last_tag[b] = bt;
    }
}

// ---------------- K2b: parallel backpointer recovery ----------------
// bp[t][n] = first p with fl(fl(s_{t-1}[p]+T[p][n])+e[t][n]) == s_t[n]
__global__ __launch_bounds__(256) void k_bp(
    const float* __restrict__ emT, const float* __restrict__ sc,
    const float* __restrict__ trans, uint8_t* __restrict__ bp)
{
    int wave = threadIdx.x >> 6;
    int lane = threadIdx.x & 63;
    int ne   = lane < NC ? lane : NC-1;

    int bidx  = blockIdx.x;
    int b     = bidx >> 7;                              // 128 blocks per batch
    int tbase = (bidx & 127) * (4*T_PER) + wave*T_PER;

    const float* emb = emT + (size_t)b * NC * L;
    const float* scp = sc  + (size_t)b * NC * L;
    uint8_t*     bpb = bp  + (size_t)b * L * NC;

    float tc[NC];
    #pragma unroll
    for (int pp = 0; pp < NC; ++pp) tc[pp] = trans[pp*NC + ne];

    for (int t = tbase; t < tbase + T_PER; ++t) {
        if (t == 0) continue;
        float target = scp[(t>>2)*84 + ne*4 + (t&3)];
        float e      = emb[(size_t)ne * L + t];
        const float* sp = scp + ((t-1)>>2)*84 + ((t-1)&3);
        int fi = 0;
        #pragma unroll
        for (int pp = NC-1; pp >= 0; --pp) {
            float cand = (sp[pp*4] + tc[pp]) + e;
            if (cand == target) fi = pp;
        }
        if (lane < NC) bpb[(size_t)t * NC + ne] = (uint8_t)fi;
    }
}

// ---------------- K3: chunk-parallel backtrack (integer, exact) ----------------
__global__ __launch_bounds__(64) void k_backtrack(
    const uint8_t* __restrict__ bp, const int* __restrict__ last_tag,
    int* __restrict__ out)
{
    int blk = blockIdx.x;
    int b   = blk >> 6;
    int k   = blk & (NCHUNKS-1);
    int cs  = k * CHUNK;
    int ce  = cs + CHUNK;
    int sp  = ce - 1 + WARM; if (sp > L-1) sp = L-1;
    int tag = (sp == L-1) ? last_tag[b] : 0;
    const uint8_t* bpb = bp + (size_t)b * L * NC;
    int* ob = out + (size_t)b * L;
    for (int t = sp;; --t) {
        if (t < ce) { if (threadIdx.x == 0) ob[t] = tag; }
        if (t == cs) break;
        tag = (int)bpb[(size_t)t * NC + tag];
    }
}

extern "C" void kernel_launch(void* const* d_in, const int* in_sizes, int n_in,
                              void* d_out, int out_size, void* d_ws, size_t ws_size,
                              hipStream_t stream) {
    const float* x  = (const float*)d_in[0];
    const float* w1 = (const float*)d_in[1];
    const float* b1 = (const float*)d_in[2];
    const float* w2 = (const float*)d_in[3];
    const float* b2 = (const float*)d_in[4];
    const float* st = (const float*)d_in[5];
    const float* en = (const float*)d_in[6];
    const float* tr = (const float*)d_in[7];
    int* out = (int*)d_out;

    char* ws = (char*)d_ws;
    float*   em = (float*)ws;                                    // em_T: 22,020,096 B
    float*   sc = (float*)(ws + (size_t)NB*L*NC*4);              // packed scores: 22,020,096 B
    uint8_t* bp = (uint8_t*)(ws + (size_t)NB*L*NC*8);            // 5,505,024 B
    int*     lt = (int*)(ws + (size_t)NB*L*NC*9);                // int[NB]

    k_conv     <<<dim3(NB*L/256),   dim3(256), 0, stream>>>(x, w1, b1, w2, b2, em);
    k_scores   <<<dim3(NB),         dim3(64),  0, stream>>>(em, st, en, tr, sc, lt);
    k_bp       <<<dim3(NB*128),     dim3(256), 0, stream>>>(em, sc, tr, bp);
    k_backtrack<<<dim3(NB*NCHUNKS), dim3(64),  0, stream>>>(bp, lt, out);
}

// Round 16
// 2548.302 us; speedup vs baseline: 1.6032x; 1.3142x over previous
//
#include <hip/hip_runtime.h>
#include <stdint.h>

#define NB 16
#define HH 128
#define WW 128
#define L (HH*WW)        // 16384
#define CIN 3
#define HID 256
#define NC 21
#define CHUNK 256
#define NCHUNKS (L/CHUNK)   // 64
#define T_PER 32            // t's per wave in k_bp
#define NPACK (L/4)         // 4096 packs of 4 timesteps

// ---------------- K1: conv -> fp32 emissions, stored TRANSPOSED em_T[b][c][t] ----------------
// fp64 accumulate (round once to fp32 = correctly rounded), fp32 elementwise bias in ref order.
__global__ __launch_bounds__(256) void k_conv(
    const float* __restrict__ x, const float* __restrict__ w1,
    const float* __restrict__ b1, const float* __restrict__ w2,
    const float* __restrict__ b2, float* __restrict__ emT)
{
    int tid = threadIdx.x;
    int g  = blockIdx.x * 256 + tid;      // 0..B*L-1
    int b  = g >> 14;
    int t  = g & (L-1);
    int y  = t >> 7;
    int xx = t & (WW-1);

    double p[27];
    const float* xb = x + (size_t)b * CIN * L;
    #pragma unroll
    for (int ic = 0; ic < CIN; ++ic) {
        #pragma unroll
        for (int ky = 0; ky < 3; ++ky) {
            #pragma unroll
            for (int kx = 0; kx < 3; ++kx) {
                int yy = y + ky - 1, xc = xx + kx - 1;
                float v = 0.f;
                if (yy >= 0 && yy < HH && xc >= 0 && xc < WW)
                    v = xb[ic * L + yy * WW + xc];
                p[ic*9 + ky*3 + kx] = (double)v;
            }
        }
    }

    double acc[NC];
    #pragma unroll
    for (int c = 0; c < NC; ++c) acc[c] = 0.0;

    #pragma unroll 2
    for (int oc = 0; oc < HID; ++oc) {
        double hv = 0.0;                              // conv1 accum
        #pragma unroll
        for (int j = 0; j < 27; ++j) hv += (double)w1[oc*27 + j] * p[j];
        float h32 = (float)hv;                        // round conv1 to fp32
        h32 = h32 + b1[oc];                           // fp32 elementwise bias
        h32 = fmaxf(h32, 0.f);                        // relu (fp32)
        double hd = (double)h32;
        #pragma unroll
        for (int c = 0; c < NC; ++c) acc[c] += (double)w2[c*HID + oc] * hd;
    }
    float* dstb = emT + (size_t)b * NC * L;
    #pragma unroll
    for (int c = 0; c < NC; ++c) {
        float e32 = (float)acc[c];                    // round conv2 to fp32
        dstb[(size_t)c * L + t] = e32 + b2[c];        // transposed store (coalesced in t)
    }
}

// ---------------- K2a: p-split bpermute recursion (R11 verbatim — measured 2144 us) ----------------
// s'[n] = fl( max_p fl(s[p]+T[p][n]) + e[n] ) — bitwise equal to ref by RNE monotonicity.
// Measured transport floor: 9 cross-lane ops (7 gather + 2 combine) x ~14 cyc issue + 2
// dependent DS-latency levels ~ 314 cyc/step. ops = 21/g+(g-1) is minimized at g=7 -> 9;
// this structure is optimal for the measured primitive costs (R6-R15 ladder).
__global__ __launch_bounds__(64) void k_scores(
    const float* __restrict__ emT, const float* __restrict__ start,
    const float* __restrict__ endt, const float* __restrict__ trans,
    float* __restrict__ sc, int* __restrict__ last_tag)
{
    __shared__ float fin[NC];
    int l = threadIdx.x;
    int b = blockIdx.x;
    int g = l / 21; if (g > 2) g = 2;        // lane 63 shadows (g=2,n=20)
    int n = l - g*21; if (n > 20) n = 20;

    const float4* er4 = (const float4*)(emT + ((size_t)b * NC + n) * L);
    float*        scp = sc + (size_t)b * NC * L;          // 84 floats per pack

    float tc[7];
    #pragma unroll
    for (int i = 0; i < 7; ++i) tc[i] = trans[(g*7 + i)*NC + n];
    #pragma unroll
    for (int i = 0; i < 7; ++i) asm volatile("" : "+v"(tc[i]));   // pin in VGPRs

    int ga[7];
    #pragma unroll
    for (int i = 0; i < 7; ++i) ga[i] = (g*7 + i) * 4;    // gather addrs (copy-0 lanes)
    #pragma unroll
    for (int i = 0; i < 7; ++i) asm volatile("" : "+v"(ga[i]));
    int g1 = g + 1; if (g1 > 2) g1 -= 3;
    int g2 = g + 2; if (g2 > 2) g2 -= 3;
    int ca1 = (n + 21*g1) * 4;                            // combine addrs (other copies)
    int ca2 = (n + 21*g2) * 4;
    asm volatile("" : "+v"(ca1), "+v"(ca2));

    float sv;   // my state's current score s[n]

    #define BPERM(A,V) __int_as_float(__builtin_amdgcn_ds_bpermute((A), __float_as_int(V)))

    #define STEP(EV, OUT) { \
        float w0 = BPERM(ga[0], sv) + tc[0]; \
        float w1 = BPERM(ga[1], sv) + tc[1]; \
        float w2 = BPERM(ga[2], sv) + tc[2]; \
        float w3 = BPERM(ga[3], sv) + tc[3]; \
        float w4 = BPERM(ga[4], sv) + tc[4]; \
        float w5 = BPERM(ga[5], sv) + tc[5]; \
        float w6 = BPERM(ga[6], sv) + tc[6]; \
        float pa = fmaxf(fmaxf(w0, w1), w2); \
        float pb = fmaxf(fmaxf(w3, w4), w5); \
        float pr = fmaxf(fmaxf(pa, pb), w6);        /* exact max over my 7 p's */ \
        float o1 = BPERM(ca1, pr); \
        float o2 = BPERM(ca2, pr); \
        OUT = fmaxf(fmaxf(pr, o1), o2) + (EV);      /* exact max over 21, then fl(+e) */ \
        sv = OUT; }

    float4 ebuf0 = er4[0];
    float4 ebuf1 = er4[1];

    // ---- pack 0 (t=0 init + t=1..3) ----
    float v0 = ebuf0.x + start[n];      // s0 = fl(em[0]+start), ref order
    sv = v0;
    {
        float4 ev = ebuf0;
        ebuf0 = er4[2];
        float a1v, a2v, a3v;
        STEP(ev.y, a1v)
        STEP(ev.z, a2v)
        STEP(ev.w, a3v)
        if (l < NC) *(float4*)(scp + n*4) = make_float4(v0, a1v, a2v, a3v);
    }

    // ---- packs 1..4095 ----
    for (int k = 1; k < NPACK; ++k) {
        float4 ev = (k & 1) ? ebuf1 : ebuf0;
        int kp = k + 2; if (kp > NPACK-1) kp = NPACK-1;
        if (k & 1) ebuf1 = er4[kp]; else ebuf0 = er4[kp];

        float b0, b1_, b2_, b3;
        STEP(ev.x, b0)
        STEP(ev.y, b1_)
        STEP(ev.z, b2_)
        STEP(ev.w, b3)
        if (l < NC) *(float4*)(scp + k*84 + n*4) = make_float4(b0, b1_, b2_, b3);
    }
    #undef STEP
    #undef BPERM

    if (l < NC) fin[n] = sv;
    __syncthreads();
    if (l == 0) {
        float bv = fin[0] + endt[0]; int bt = 0;
        #pragma unroll
        for (int j = 1; j < NC; ++j) {
            float v = fin[j] + endt[j];
            if (v > bv) { bv = v; bt = j; }
        }
        last_tag[b] = bt;
    }
}

// ---------------- K2b: parallel backpointer recovery ----------------
// bp[t][n] = first p with fl(fl(s_{t-1}[p]+T[p][n])+e[t][n]) == s_t[n]
__global__ __launch_bounds__(256) void k_bp(
    const float* __restrict__ emT, const float* __restrict__ sc,
    const float* __restrict__ trans, uint8_t* __restrict__ bp)
{
    int wave = threadIdx.x >> 6;
    int lane = threadIdx.x & 63;
    int ne   = lane < NC ? lane : NC-1;

    int bidx  = blockIdx.x;
    int b     = bidx >> 7;                              // 128 blocks per batch
    int tbase = (bidx & 127) * (4*T_PER) + wave*T_PER;

    const float* emb = emT + (size_t)b * NC * L;
    const float* scp = sc  + (size_t)b * NC * L;
    uint8_t*     bpb = bp  + (size_t)b * L * NC;

    float tc[NC];
    #pragma unroll
    for (int pp = 0; pp < NC; ++pp) tc[pp] = trans[pp*NC + ne];

    for (int t = tbase; t < tbase + T_PER; ++t) {
        if (t == 0) continue;
        float target = scp[(t>>2)*84 + ne*4 + (t&3)];
        float e      = emb[(size_t)ne * L + t];
        const float* sp = scp + ((t-1)>>2)*84 + ((t-1)&3);
        int fi = 0;
        #pragma unroll
        for (int pp = NC-1; pp >= 0; --pp) {
            float cand = (sp[pp*4] + tc[pp]) + e;
            if (cand == target) fi = pp;
        }
        if (lane < NC) bpb[(size_t)t * NC + ne] = (uint8_t)fi;
    }
}

// ---------------- K3a: per-chunk jump tables (EXACT — replaces WARM heuristic) ----------------
// For chunk k>=1 of batch b: J[b][k][h] = tag at cs-1 when tag at ce-1 is h,
// via 256 exact bp hops. 21 hypotheses chase in parallel in LDS-staged bp.
__global__ __launch_bounds__(64) void k_jump(
    const uint8_t* __restrict__ bp, uint8_t* __restrict__ J)
{
    __shared__ uint32_t lds4[CHUNK*NC/4];    // 5376 B of bp rows [cs..ce)
    int l   = threadIdx.x;
    int bid = blockIdx.x;
    int b   = bid / (NCHUNKS-1);
    int k   = bid % (NCHUNKS-1) + 1;         // chunks 1..63
    int cs  = k * CHUNK;

    const uint32_t* src = (const uint32_t*)(bp + (size_t)b * L * NC + (size_t)cs * NC);
    for (int i = l; i < CHUNK*NC/4; i += 64) lds4[i] = src[i];
    __syncthreads();

    if (l < NC) {
        const uint8_t* lb = (const uint8_t*)lds4;
        int tag = l;
        for (int r = CHUNK-1; r >= 0; --r)           // t = cs+r, hops t=ce-1..cs
            tag = lb[r*NC + tag];
        J[((size_t)b * NCHUNKS + k) * NC + l] = (uint8_t)tag;
    }
}

// ---------------- K3b: thread chunk entries through jump tables (16 lanes) ----------------
// ent[b][k] = exact tag at position (k+1)*CHUNK - 1.
__global__ __launch_bounds__(64) void k_seq(
    const uint8_t* __restrict__ J, const int* __restrict__ last_tag,
    uint8_t* __restrict__ ent)
{
    int b = threadIdx.x;
    if (b < NB) {
        int tag = last_tag[b];                       // tag at t = L-1 (chunk 63 entry)
        ent[b * NCHUNKS + 63] = (uint8_t)tag;
        for (int k = NCHUNKS-1; k >= 1; --k) {
            tag = J[((size_t)b * NCHUNKS + k) * NC + tag];  // -> tag at cs_k - 1 = entry of k-1
            ent[b * NCHUNKS + (k-1)] = (uint8_t)tag;
        }
    }
}

// ---------------- K3c: per-chunk output chase from exact seed, coalesced writes ----------------
__global__ __launch_bounds__(64) void k_out(
    const uint8_t* __restrict__ bp, const uint8_t* __restrict__ ent,
    int* __restrict__ out)
{
    __shared__ uint32_t lds4[CHUNK*NC/4];    // bp rows for this chunk
    __shared__ int tags[CHUNK];
    int l   = threadIdx.x;
    int bid = blockIdx.x;
    int b   = bid >> 6;
    int k   = bid & (NCHUNKS-1);
    int cs  = k * CHUNK;

    const uint32_t* src = (const uint32_t*)(bp + (size_t)b * L * NC + (size_t)cs * NC);
    for (int i = l; i < CHUNK*NC/4; i += 64) lds4[i] = src[i];
    __syncthreads();

    if (l == 0) {
        const uint8_t* lb = (const uint8_t*)lds4;
        int tag = ent[b * NCHUNKS + k];              // exact tag at ce-1
        for (int r = CHUNK-1; r >= 0; --r) {         // t = cs+r down to cs
            tags[r] = tag;
            int t = cs + r;
            if (t > 0) tag = lb[r*NC + tag];         // tag_{t-1} = bp[t][tag_t]
        }
    }
    __syncthreads();

    int4* ob = (int4*)(out + (size_t)b * L + cs);
    const int4* tb = (const int4*)tags;
    ob[l] = tb[l];                                   // 64 lanes x int4 = 256 ints
}

extern "C" void kernel_launch(void* const* d_in, const int* in_sizes, int n_in,
                              void* d_out, int out_size, void* d_ws, size_t ws_size,
                              hipStream_t stream) {
    const float* x  = (const float*)d_in[0];
    const float* w1 = (const float*)d_in[1];
    const float* b1 = (const float*)d_in[2];
    const float* w2 = (const float*)d_in[3];
    const float* b2 = (const float*)d_in[4];
    const float* st = (const float*)d_in[5];
    const float* en = (const float*)d_in[6];
    const float* tr = (const float*)d_in[7];
    int* out = (int*)d_out;

    char* ws = (char*)d_ws;
    float*   em = (float*)ws;                                    // em_T: 22,020,096 B
    float*   sc = (float*)(ws + (size_t)NB*L*NC*4);              // packed scores: 22,020,096 B
    uint8_t* bp = (uint8_t*)(ws + (size_t)NB*L*NC*8);            // 5,505,024 B
    int*     lt = (int*)(ws + (size_t)NB*L*NC*9);                // int[NB]
    // J/ent alias the em region: em is dead after k_bp completes (stream-ordered).
    uint8_t* J   = (uint8_t*)ws;                                 // NB*64*21 = 21,504 B
    uint8_t* ent = (uint8_t*)ws + 21504;                         // NB*64 = 1,024 B

    k_conv  <<<dim3(NB*L/256),       dim3(256), 0, stream>>>(x, w1, b1, w2, b2, em);
    k_scores<<<dim3(NB),             dim3(64),  0, stream>>>(em, st, en, tr, sc, lt);
    k_bp    <<<dim3(NB*128),         dim3(256), 0, stream>>>(em, sc, tr, bp);
    k_jump  <<<dim3(NB*(NCHUNKS-1)), dim3(64),  0, stream>>>(bp, J);
    k_seq   <<<dim3(1),              dim3(64),  0, stream>>>(J, lt, ent);
    k_out   <<<dim3(NB*NCHUNKS),     dim3(64),  0, stream>>>(bp, ent, out);
}

// Round 17
// 2532.186 us; speedup vs baseline: 1.6135x; 1.0064x over previous
//
#include <hip/hip_runtime.h>
#include <stdint.h>

#define NB 16
#define HH 128
#define WW 128
#define L (HH*WW)        // 16384
#define CIN 3
#define HID 256
#define NC 21
#define CHUNK 256
#define NCHUNKS (L/CHUNK)   // 64
#define T_PER 32            // t's per wave in k_bp
#define NPACK (L/4)         // 4096 packs of 4 timesteps

// ---------------- K1: conv -> fp32 emissions, TRANSPOSED em_T[b][c][t], LDS input tile ----------------
// fp64 accumulate (round once to fp32 = correctly rounded), fp32 elementwise bias in ref order.
// Block covers 2 image rows; x patch staged in LDS (6 coalesced loads/thread vs 27 global).
// Values and FMA order identical to R16 -> bit-identical emissions.
__global__ __launch_bounds__(256) void k_conv(
    const float* __restrict__ x, const float* __restrict__ w1,
    const float* __restrict__ b1, const float* __restrict__ w2,
    const float* __restrict__ b2, float* __restrict__ emT)
{
    __shared__ float xs[CIN*4*WW];        // 3 ic x 4 rows x 128 cols = 6144 B
    int tid = threadIdx.x;
    int g  = blockIdx.x * 256 + tid;      // 0..B*L-1
    int b  = g >> 14;
    int t0 = (blockIdx.x * 256) & (L-1);  // first t of block (multiple of 256)
    int y0 = t0 >> 7;                     // first of the block's 2 rows
    int dy = tid >> 7;                    // 0 or 1
    int y  = y0 + dy;
    int xx = tid & (WW-1);
    int t  = t0 + tid;

    const float* xb = x + (size_t)b * CIN * L;
    for (int i = tid; i < CIN*4*WW; i += 256) {
        int ic  = i >> 9;                 // /512
        int rem = i & 511;
        int rr  = rem >> 7;               // 0..3
        int cc  = rem & 127;
        int row = y0 - 1 + rr;
        xs[i] = (row >= 0 && row < HH) ? xb[ic*L + (row<<7) + cc] : 0.f;
    }
    __syncthreads();

    double p[27];
    #pragma unroll
    for (int ic = 0; ic < CIN; ++ic) {
        #pragma unroll
        for (int ky = 0; ky < 3; ++ky) {
            #pragma unroll
            for (int kx = 0; kx < 3; ++kx) {
                int xc = xx + kx - 1;
                float v = (xc >= 0 && xc < WW) ? xs[ic*512 + (dy+ky)*128 + xc] : 0.f;
                p[ic*9 + ky*3 + kx] = (double)v;
            }
        }
    }

    double acc[NC];
    #pragma unroll
    for (int c = 0; c < NC; ++c) acc[c] = 0.0;

    #pragma unroll 2
    for (int oc = 0; oc < HID; ++oc) {
        double hv = 0.0;                              // conv1 accum
        #pragma unroll
        for (int j = 0; j < 27; ++j) hv += (double)w1[oc*27 + j] * p[j];
        float h32 = (float)hv;                        // round conv1 to fp32
        h32 = h32 + b1[oc];                           // fp32 elementwise bias
        h32 = fmaxf(h32, 0.f);                        // relu (fp32)
        double hd = (double)h32;
        #pragma unroll
        for (int c = 0; c < NC; ++c) acc[c] += (double)w2[c*HID + oc] * hd;
    }
    float* dstb = emT + (size_t)b * NC * L;
    #pragma unroll
    for (int c = 0; c < NC; ++c) {
        float e32 = (float)acc[c];                    // round conv2 to fp32
        dstb[(size_t)c * L + t] = e32 + b2[c];        // transposed store (coalesced in t)
    }
}

// ---------------- K2a: p-split bpermute recursion (R11 verbatim — measured floor, 2144 us) ----------------
// s'[n] = fl( max_p fl(s[p]+T[p][n]) + e[n] ) — bitwise equal to ref by RNE monotonicity.
// 9 cross-lane ops (7 gather + 2 combine) x ~14 cyc issue + 2 dependent DS levels ~ 314 cyc/step;
// ops = 21/g+(g-1) minimized at g=7 -> this structure is optimal per the R6-R15 ladder.
__global__ __launch_bounds__(64) void k_scores(
    const float* __restrict__ emT, const float* __restrict__ start,
    const float* __restrict__ endt, const float* __restrict__ trans,
    float* __restrict__ sc, int* __restrict__ last_tag)
{
    __shared__ float fin[NC];
    int l = threadIdx.x;
    int b = blockIdx.x;
    int g = l / 21; if (g > 2) g = 2;        // lane 63 shadows (g=2,n=20)
    int n = l - g*21; if (n > 20) n = 20;

    const float4* er4 = (const float4*)(emT + ((size_t)b * NC + n) * L);
    float*        scp = sc + (size_t)b * NC * L;          // 84 floats per pack

    float tc[7];
    #pragma unroll
    for (int i = 0; i < 7; ++i) tc[i] = trans[(g*7 + i)*NC + n];
    #pragma unroll
    for (int i = 0; i < 7; ++i) asm volatile("" : "+v"(tc[i]));   // pin in VGPRs

    int ga[7];
    #pragma unroll
    for (int i = 0; i < 7; ++i) ga[i] = (g*7 + i) * 4;    // gather addrs (copy-0 lanes)
    #pragma unroll
    for (int i = 0; i < 7; ++i) asm volatile("" : "+v"(ga[i]));
    int g1 = g + 1; if (g1 > 2) g1 -= 3;
    int g2 = g + 2; if (g2 > 2) g2 -= 3;
    int ca1 = (n + 21*g1) * 4;                            // combine addrs (other copies)
    int ca2 = (n + 21*g2) * 4;
    asm volatile("" : "+v"(ca1), "+v"(ca2));

    float sv;   // my state's current score s[n]

    #define BPERM(A,V) __int_as_float(__builtin_amdgcn_ds_bpermute((A), __float_as_int(V)))

    #define STEP(EV, OUT) { \
        float w0 = BPERM(ga[0], sv) + tc[0]; \
        float w1 = BPERM(ga[1], sv) + tc[1]; \
        float w2 = BPERM(ga[2], sv) + tc[2]; \
        float w3 = BPERM(ga[3], sv) + tc[3]; \
        float w4 = BPERM(ga[4], sv) + tc[4]; \
        float w5 = BPERM(ga[5], sv) + tc[5]; \
        float w6 = BPERM(ga[6], sv) + tc[6]; \
        float pa = fmaxf(fmaxf(w0, w1), w2); \
        float pb = fmaxf(fmaxf(w3, w4), w5); \
        float pr = fmaxf(fmaxf(pa, pb), w6);        /* exact max over my 7 p's */ \
        float o1 = BPERM(ca1, pr); \
        float o2 = BPERM(ca2, pr); \
        OUT = fmaxf(fmaxf(pr, o1), o2) + (EV);      /* exact max over 21, then fl(+e) */ \
        sv = OUT; }

    float4 ebuf0 = er4[0];
    float4 ebuf1 = er4[1];

    // ---- pack 0 (t=0 init + t=1..3) ----
    float v0 = ebuf0.x + start[n];      // s0 = fl(em[0]+start), ref order
    sv = v0;
    {
        float4 ev = ebuf0;
        ebuf0 = er4[2];
        float a1v, a2v, a3v;
        STEP(ev.y, a1v)
        STEP(ev.z, a2v)
        STEP(ev.w, a3v)
        if (l < NC) *(float4*)(scp + n*4) = make_float4(v0, a1v, a2v, a3v);
    }

    // ---- packs 1..4095 ----
    for (int k = 1; k < NPACK; ++k) {
        float4 ev = (k & 1) ? ebuf1 : ebuf0;
        int kp = k + 2; if (kp > NPACK-1) kp = NPACK-1;
        if (k & 1) ebuf1 = er4[kp]; else ebuf0 = er4[kp];

        float b0, b1_, b2_, b3;
        STEP(ev.x, b0)
        STEP(ev.y, b1_)
        STEP(ev.z, b2_)
        STEP(ev.w, b3)
        if (l < NC) *(float4*)(scp + k*84 + n*4) = make_float4(b0, b1_, b2_, b3);
    }
    #undef STEP
    #undef BPERM

    if (l < NC) fin[n] = sv;
    __syncthreads();
    if (l == 0) {
        float bv = fin[0] + endt[0]; int bt = 0;
        #pragma unroll
        for (int j = 1; j < NC; ++j) {
            float v = fin[j] + endt[j];
            if (v > bv) { bv = v; bt = j; }
        }
        last_tag[b] = bt;
    }
}

// ---------------- K2b: parallel backpointer recovery ----------------
// bp[t][n] = first p with fl(fl(s_{t-1}[p]+T[p][n])+e[t][n]) == s_t[n]
__global__ __launch_bounds__(256) void k_bp(
    const float* __restrict__ emT, const float* __restrict__ sc,
    const float* __restrict__ trans, uint8_t* __restrict__ bp)
{
    int wave = threadIdx.x >> 6;
    int lane = threadIdx.x & 63;
    int ne   = lane < NC ? lane : NC-1;

    int bidx  = blockIdx.x;
    int b     = bidx >> 7;                              // 128 blocks per batch
    int tbase = (bidx & 127) * (4*T_PER) + wave*T_PER;

    const float* emb = emT + (size_t)b * NC * L;
    const float* scp = sc  + (size_t)b * NC * L;
    uint8_t*     bpb = bp  + (size_t)b * L * NC;

    float tc[NC];
    #pragma unroll
    for (int pp = 0; pp < NC; ++pp) tc[pp] = trans[pp*NC + ne];

    for (int t = tbase; t < tbase + T_PER; ++t) {
        if (t == 0) continue;
        float target = scp[(t>>2)*84 + ne*4 + (t&3)];
        float e      = emb[(size_t)ne * L + t];
        const float* sp = scp + ((t-1)>>2)*84 + ((t-1)&3);
        int fi = 0;
        #pragma unroll
        for (int pp = NC-1; pp >= 0; --pp) {
            float cand = (sp[pp*4] + tc[pp]) + e;
            if (cand == target) fi = pp;
        }
        if (lane < NC) bpb[(size_t)t * NC + ne] = (uint8_t)fi;
    }
}

// ---------------- K3a: per-chunk jump tables, SEGMENTED chase (exact) ----------------
// 8 segment tables of 32 hops built by 63 lanes (3 pipelined chases/lane), composed in 8 hops.
// Wall ~ 32+8 dependent LDS hops vs 256 before.
__global__ __launch_bounds__(64) void k_jump(
    const uint8_t* __restrict__ bp, uint8_t* __restrict__ J)
{
    __shared__ uint32_t lds4[CHUNK*NC/4];    // 5376 B of bp rows [cs..ce)
    __shared__ uint8_t  segJ[8*NC];          // 168 B
    int l   = threadIdx.x;
    int bid = blockIdx.x;
    int b   = bid / (NCHUNKS-1);
    int k   = bid % (NCHUNKS-1) + 1;         // chunks 1..63
    int cs  = k * CHUNK;

    const uint32_t* src = (const uint32_t*)(bp + (size_t)b * L * NC + (size_t)cs * NC);
    for (int i = l; i < CHUNK*NC/4; i += 64) lds4[i] = src[i];
    __syncthreads();
    const uint8_t* lb = (const uint8_t*)lds4;

    // 168 = 8 segs x 21 hyps; chase c -> (s=c/21, h=c%21), rows s*32+31 .. s*32
    int c0 = l, c1 = l + 63, c2 = l + 126;
    bool v2 = (c2 < 8*NC);
    int t0 = c0 % NC, t1 = c1 % NC, t2 = v2 ? (c2 % NC) : 0;
    int r0 = (c0 / NC) * 32, r1 = (c1 / NC) * 32, r2 = v2 ? (c2 / NC) * 32 : 0;
    for (int i = 31; i >= 0; --i) {          // 3 independent chains -> pipelined
        t0 = lb[(r0+i)*NC + t0];
        t1 = lb[(r1+i)*NC + t1];
        if (v2) t2 = lb[(r2+i)*NC + t2];
    }
    segJ[c0] = (uint8_t)t0;
    segJ[c1] = (uint8_t)t1;
    if (v2) segJ[c2] = (uint8_t)t2;
    __syncthreads();

    if (l < NC) {
        int tag = l;
        #pragma unroll
        for (int s = 7; s >= 0; --s) tag = segJ[s*NC + tag];
        J[((size_t)b * NCHUNKS + k) * NC + l] = (uint8_t)tag;
    }
}

// ---------------- K3b: thread chunk entries through jump tables (LDS-staged J) ----------------
__global__ __launch_bounds__(64) void k_seq(
    const uint8_t* __restrict__ J, const int* __restrict__ last_tag,
    uint8_t* __restrict__ ent)
{
    __shared__ uint32_t ldsJ4[NB*NCHUNKS*NC/4];   // 21504 B
    int l = threadIdx.x;
    const uint32_t* src = (const uint32_t*)J;
    for (int i = l; i < NB*NCHUNKS*NC/4; i += 64) ldsJ4[i] = src[i];
    __syncthreads();
    const uint8_t* lj = (const uint8_t*)ldsJ4;

    if (l < NB) {
        int b = l;
        int tag = last_tag[b];                       // tag at t = L-1
        ent[b * NCHUNKS + 63] = (uint8_t)tag;
        for (int k = NCHUNKS-1; k >= 1; --k) {
            tag = lj[((size_t)b * NCHUNKS + k) * NC + tag];
            ent[b * NCHUNKS + (k-1)] = (uint8_t)tag;
        }
    }
}

// ---------------- K3c: per-chunk output, SEGMENTED re-walk from exact seed ----------------
__global__ __launch_bounds__(64) void k_out(
    const uint8_t* __restrict__ bp, const uint8_t* __restrict__ ent,
    int* __restrict__ out)
{
    __shared__ uint32_t lds4[CHUNK*NC/4];
    __shared__ uint8_t  segJ[8*NC];
    __shared__ uint8_t  E[8];
    __shared__ int      tags[CHUNK];
    int l   = threadIdx.x;
    int bid = blockIdx.x;
    int b   = bid >> 6;
    int k   = bid & (NCHUNKS-1);
    int cs  = k * CHUNK;

    const uint32_t* src = (const uint32_t*)(bp + (size_t)b * L * NC + (size_t)cs * NC);
    for (int i = l; i < CHUNK*NC/4; i += 64) lds4[i] = src[i];
    __syncthreads();
    const uint8_t* lb = (const uint8_t*)lds4;

    // phase 2: segment tables (chunk 0 seg 0 crosses t=0: its result is never used)
    int c0 = l, c1 = l + 63, c2 = l + 126;
    bool v2 = (c2 < 8*NC);
    int t0 = c0 % NC, t1 = c1 % NC, t2 = v2 ? (c2 % NC) : 0;
    int r0 = (c0 / NC) * 32, r1 = (c1 / NC) * 32, r2 = v2 ? (c2 / NC) * 32 : 0;
    for (int i = 31; i >= 0; --i) {
        t0 = lb[(r0+i)*NC + t0];
        t1 = lb[(r1+i)*NC + t1];
        if (v2) t2 = lb[(r2+i)*NC + t2];
    }
    segJ[c0] = (uint8_t)(t0 & 31);           // mask: chunk-0/seg-0 garbage stays in-bounds
    segJ[c1] = (uint8_t)(t1 & 31);
    if (v2) segJ[c2] = (uint8_t)(t2 & 31);
    __syncthreads();

    // phase 3: compose segment entry tags E[s] = tag at position cs + 32s + 31
    if (l == 0) {
        int tag = ent[b * NCHUNKS + k];              // exact tag at ce-1
        E[7] = (uint8_t)tag;
        #pragma unroll
        for (int s = 7; s >= 1; --s) { tag = segJ[s*NC + tag]; E[s-1] = (uint8_t)tag; }
    }
    __syncthreads();

    // phase 4: 8 lanes re-walk their 32 rows
    if (l < 8) {
        int tag = E[l];
        int rb  = l * 32;
        for (int i = 31; i >= 0; --i) {              // t = cs+rb+i down to cs+rb
            tags[rb + i] = tag;
            tag = lb[(rb+i)*NC + tag];               // hop at t=0 (chunk 0) unused
        }
    }
    __syncthreads();

    int4* ob = (int4*)(out + (size_t)b * L + cs);
    ob[l] = ((const int4*)tags)[l];                  // 64 lanes x int4 = 256 ints
}

extern "C" void kernel_launch(void* const* d_in, const int* in_sizes, int n_in,
                              void* d_out, int out_size, void* d_ws, size_t ws_size,
                              hipStream_t stream) {
    const float* x  = (const float*)d_in[0];
    const float* w1 = (const float*)d_in[1];
    const float* b1 = (const float*)d_in[2];
    const float* w2 = (const float*)d_in[3];
    const float* b2 = (const float*)d_in[4];
    const float* st = (const float*)d_in[5];
    const float* en = (const float*)d_in[6];
    const float* tr = (const float*)d_in[7];
    int* out = (int*)d_out;

    char* ws = (char*)d_ws;
    float*   em = (float*)ws;                                    // em_T: 22,020,096 B
    float*   sc = (float*)(ws + (size_t)NB*L*NC*4);              // packed scores: 22,020,096 B
    uint8_t* bp = (uint8_t*)(ws + (size_t)NB*L*NC*8);            // 5,505,024 B
    int*     lt = (int*)(ws + (size_t)NB*L*NC*9);                // int[NB]
    // J/ent alias the em region: em is dead after k_bp completes (stream-ordered).
    uint8_t* J   = (uint8_t*)ws;                                 // NB*64*21 = 21,504 B
    uint8_t* ent = (uint8_t*)ws + 21504;                         // NB*64 = 1,024 B

    k_conv  <<<dim3(NB*L/256),       dim3(256), 0, stream>>>(x, w1, b1, w2, b2, em);
    k_scores<<<dim3(NB),             dim3(64),  0, stream>>>(em, st, en, tr, sc, lt);
    k_bp    <<<dim3(NB*128),         dim3(256), 0, stream>>>(em, sc, tr, bp);
    k_jump  <<<dim3(NB*(NCHUNKS-1)), dim3(64),  0, stream>>>(bp, J);
    k_seq   <<<dim3(1),              dim3(64),  0, stream>>>(J, lt, ent);
    k_out   <<<dim3(NB*NCHUNKS),     dim3(64),  0, stream>>>(bp, ent, out);
}